// Round 4
// baseline (512.209 us; speedup 1.0000x reference)
//
#include <hip/hip_runtime.h>
#include <stdint.h>

// Problem constants (B,N,H,W) = (4,256,256,256)
#define BATCH 4
#define NCH   256
#define HH    256
#define WW    256
#define HWSZ  (HH * WW)          // 65536
#define NPIX  (BATCH * HWSZ)     // 262144 output-mean denominator

// ---------------------------------------------------------------------------
// Kernel 1 (UNCHANGED from R3): one block per (b,n) channel. flat_index =
// sum(value * index), branchless, int4 loads -> 4 KiB contiguous per
// wave-step, sequential stream. ~BW-bound.
// ---------------------------------------------------------------------------
__global__ __launch_bounds__(256) void find_centers(
    const int* __restrict__ tc, int* __restrict__ centers)
{
    __shared__ int wsum[4];
    const int bn  = blockIdx.x;             // 0..1023
    const int tid = threadIdx.x;            // 0..255
    const int4* p = (const int4*)(tc + (size_t)bn * HWSZ);

    int acc = 0;
    #pragma unroll 8
    for (int i = 0; i < HWSZ / 4 / 256; ++i) {   // 64 iters
        const int idx = i * 256 + tid;
        const int4 v = p[idx];
        const int b4 = idx * 4;                  // <= 65532 < 2^24
        acc += v.x * b4 + v.y * (b4 + 1) + v.z * (b4 + 2) + v.w * (b4 + 3);
    }

    #pragma unroll
    for (int o = 32; o > 0; o >>= 1) acc += __shfl_down(acc, o, 64);
    if ((tid & 63) == 0) wsum[tid >> 6] = acc;
    __syncthreads();
    if (tid == 0) centers[bn] = wsum[0] + wsum[1] + wsum[2] + wsum[3];
}

// ---------------------------------------------------------------------------
// Kernel 2 (RESTRUCTURED): 1024 blocks of ONE wave (64 threads); block =
// (b, hrow); thread t owns pixels 4t..4t+3 via int4 -> each wave-load is
// 1 KiB CONTIGUOUS (was 256 B scattered in R3 -> ~2 TB/s). Unroll 16 keeps
// 16 KiB in flight per wave. Branchless inner loop; per-n
// {(h-cr)^2+eps (or +inf if padded -> rcp()=0), (float)cc} in LDS.
// ---------------------------------------------------------------------------
__global__ __launch_bounds__(64) void loss_kernel(
    const float* __restrict__ pred,
    const int*   __restrict__ targets,
    const unsigned char* __restrict__ padraw,   // layout auto-detected
    const int*   __restrict__ centers,
    float*       __restrict__ out)
{
    __shared__ float2 cinfo[NCH];

    const int tid  = threadIdx.x;               // 0..63
    const int b    = blockIdx.x >> 8;           // 256 blocks per batch
    const int hrow = blockIdx.x & 255;

    // --- pad_mask ABI layout detect, wave-local via 64-bit ballot.
    // Scan words [0,256) of the raw buffer (valid under both layouts).
    // uint8 layout: 1024 random 0/1 bytes -> some word has nonzero upper
    // 3 bytes (P[miss] ~ 8^-256). int32 layout: words are 0/1 only.
    bool upper = false;
    #pragma unroll
    for (int k = 0; k < 4; ++k) {
        const unsigned int wv = ((const unsigned int*)padraw)[tid + 64 * k];
        upper = upper || ((wv & 0xFFFFFF00u) != 0u);
    }
    const bool u8mode = (__ballot(upper) != 0ull);

    // --- per-n precompute into LDS; hrow is block-uniform
    #pragma unroll
    for (int k = 0; k < 4; ++k) {
        const int n    = tid + 64 * k;
        const int cidx = centers[b * NCH + n];  // cr*256 + cc, < 65536
        const int cr   = cidx >> 8;
        const int cc   = cidx & 255;
        int pad;
        if (u8mode) pad = (padraw[b * NCH + n] != 0);
        else        pad = (((const int*)padraw)[b * NCH + n] != 0);
        const int dh = hrow - cr;
        float fdh2e = (float)(dh * dh) + 1e-6f;
        if (pad) fdh2e = __builtin_inff();      // rcp(inf + dw^2) == 0
        cinfo[n] = make_float2(fdh2e, (float)cc);
    }
    __syncthreads();

    const int4* base =
        (const int4*)(targets + (size_t)b * NCH * HWSZ + hrow * WW) + tid;
    const float w0 = (float)(tid * 4);

    int   ts0 = 0, ts1 = 0, ts2 = 0, ts3 = 0;
    float im0 = 0.f, im1 = 0.f, im2 = 0.f, im3 = 0.f;

    #pragma unroll 16
    for (int n = 0; n < NCH; ++n) {
        const int4   v = base[n * (HWSZ / 4)];  // 1 KiB contiguous per wave
        const float2 c = cinfo[n];              // LDS broadcast
        const float d0 = w0 - c.y;
        const float d1 = d0 + 1.0f;
        const float d2 = d0 + 2.0f;
        const float d3 = d0 + 3.0f;
        im0 = __builtin_fmaf((float)v.x,
              __builtin_amdgcn_rcpf(__builtin_fmaf(d0, d0, c.x)), im0);
        im1 = __builtin_fmaf((float)v.y,
              __builtin_amdgcn_rcpf(__builtin_fmaf(d1, d1, c.x)), im1);
        im2 = __builtin_fmaf((float)v.z,
              __builtin_amdgcn_rcpf(__builtin_fmaf(d2, d2, c.x)), im2);
        im3 = __builtin_fmaf((float)v.w,
              __builtin_amdgcn_rcpf(__builtin_fmaf(d3, d3, c.x)), im3);
        ts0 += v.x; ts1 += v.y; ts2 += v.z; ts3 += v.w;
    }

    // --- epilogue: importance coeff (~tsum bitwise-NOT semantics) + BCE
    const float4 xv =
        *(const float4*)(pred + (size_t)b * HWSZ + hrow * WW + tid * 4);

    const float it0 = __builtin_fmaf((float)(~ts0), 0.5f, im0);
    const float it1 = __builtin_fmaf((float)(~ts1), 0.5f, im1);
    const float it2 = __builtin_fmaf((float)(~ts2), 0.5f, im2);
    const float it3 = __builtin_fmaf((float)(~ts3), 0.5f, im3);

    const float bce0 = fmaxf(xv.x, 0.f) - xv.x * (float)ts0 + log1pf(expf(-fabsf(xv.x)));
    const float bce1 = fmaxf(xv.y, 0.f) - xv.y * (float)ts1 + log1pf(expf(-fabsf(xv.y)));
    const float bce2 = fmaxf(xv.z, 0.f) - xv.z * (float)ts2 + log1pf(expf(-fabsf(xv.z)));
    const float bce3 = fmaxf(xv.w, 0.f) - xv.w * (float)ts3 + log1pf(expf(-fabsf(xv.w)));

    float contrib = bce0 * it0 + bce1 * it1 + bce2 * it2 + bce3 * it3;

    // --- single-wave reduction, one atomic per block
    #pragma unroll
    for (int o = 32; o > 0; o >>= 1) contrib += __shfl_down(contrib, o, 64);
    if (tid == 0) atomicAdd(out, contrib * (1.0f / (float)NPIX));
}

extern "C" void kernel_launch(void* const* d_in, const int* in_sizes, int n_in,
                              void* d_out, int out_size, void* d_ws, size_t ws_size,
                              hipStream_t stream)
{
    const float* pred = (const float*)d_in[0];               // [B,H,W] f32
    const int*   tc   = (const int*)d_in[1];                 // [B,N,H,W] i32
    const int*   tg   = (const int*)d_in[2];                 // [B,N,H,W] i32
    const unsigned char* pm = (const unsigned char*)d_in[3]; // [B,N] bool
    float* out   = (float*)d_out;
    int* centers = (int*)d_ws;                               // 1024 ints

    hipMemsetAsync(d_out, 0, sizeof(float), stream);
    find_centers<<<BATCH * NCH, 256, 0, stream>>>(tc, centers);
    loss_kernel<<<BATCH * HH, 64, 0, stream>>>(pred, tg, pm, centers, out);
}

// Round 6
// 504.805 us; speedup vs baseline: 1.0147x; 1.0147x over previous
//
#include <hip/hip_runtime.h>
#include <stdint.h>

// Problem constants (B,N,H,W) = (4,256,256,256)
#define BATCH 4
#define NCH   256
#define HH    256
#define WW    256
#define HWSZ  (HH * WW)          // 65536
#define NPIX  (BATCH * HWSZ)     // 262144 output-mean denominator

// ---------------------------------------------------------------------------
// Kernel 1 (verified R3 form): one block per (b,n) channel. The channel
// holds exactly one 1 among 0s -> flat_index = sum(value * index),
// branchless v_mad chain, int4 loads (1 KiB/wave-instruction, sequential
// stream) -> HBM-BW-bound (~43 us for 256 MiB).
// Block 0 additionally zeroes *out (d_out is re-poisoned to 0xAA before
// every timed call; the write is ordered before loss_kernel's atomics by
// the dispatch boundary). This replaces the separate 4-byte memset dispatch.
// ---------------------------------------------------------------------------
__global__ __launch_bounds__(256) void find_centers(
    const int* __restrict__ tc, int* __restrict__ centers,
    float* __restrict__ out)
{
    __shared__ int wsum[4];
    const int bn  = blockIdx.x;             // 0..1023
    const int tid = threadIdx.x;            // 0..255

    if (bn == 0 && tid == 0) *out = 0.0f;

    const int4* p = (const int4*)(tc + (size_t)bn * HWSZ);

    int acc = 0;
    #pragma unroll 8
    for (int i = 0; i < HWSZ / 4 / 256; ++i) {   // 64 iters
        const int idx = i * 256 + tid;
        const int4 v = p[idx];
        const int b4 = idx * 4;                  // <= 65532 < 2^24
        acc += v.x * b4 + v.y * (b4 + 1) + v.z * (b4 + 2) + v.w * (b4 + 3);
    }

    #pragma unroll
    for (int o = 32; o > 0; o >>= 1) acc += __shfl_down(acc, o, 64);
    if ((tid & 63) == 0) wsum[tid >> 6] = acc;
    __syncthreads();
    if (tid == 0) centers[bn] = wsum[0] + wsum[1] + wsum[2] + wsum[3];
}

// ---------------------------------------------------------------------------
// Kernel 2 (verified R3 form): 1024 blocks = one per (b, row). Branchless
// inner loop; per-n {(h-cr)^2+eps (or +inf if padded -> rcp()=0),
// (float)cc} precomputed in LDS. HBM-BW-bound (~41 us for 256 MiB;
// R4's int4/1-wave restructure was neutral, confirming BW-bound).
// ---------------------------------------------------------------------------
__global__ __launch_bounds__(256) void loss_kernel(
    const float* __restrict__ pred,
    const int*   __restrict__ targets,
    const unsigned char* __restrict__ padraw,   // layout auto-detected
    const int*   __restrict__ centers,
    float*       __restrict__ out)
{
    __shared__ float2 cinfo[NCH];
    __shared__ int    modeflag;   // 1 => pad_mask stored as uint8, 0 => int32
    __shared__ float  wsum[4];

    const int tid = threadIdx.x;
    if (tid == 0) modeflag = 0;
    __syncthreads();

    // --- pad_mask ABI layout detect. uint8 layout: 256 words of 4 random
    // 0/1 bytes -> some word has nonzero upper 3 bytes (P[miss] ~ 8^-256).
    // int32 layout: words are 0/1 only.
    {
        const unsigned int wv = ((const unsigned int*)padraw)[tid];
        if (wv & 0xFFFFFF00u) modeflag = 1;     // benign same-value race
    }
    __syncthreads();

    const int b    = blockIdx.x >> 8;           // 256 blocks per batch
    const int hrow = blockIdx.x & 255;

    // --- per-n precompute into LDS (n == tid); hrow is block-uniform
    {
        const int n    = tid;
        const int cidx = centers[b * NCH + n];  // cr*256 + cc, < 65536
        const int cr   = cidx >> 8;
        const int cc   = cidx & 255;
        int pad;
        if (modeflag) pad = (padraw[b * NCH + n] != 0);
        else          pad = (((const int*)padraw)[b * NCH + n] != 0);
        const int dh = hrow - cr;
        float fdh2e = (float)(dh * dh) + 1e-6f;
        if (pad) fdh2e = __builtin_inff();      // rcp(inf + dw^2) == 0
        cinfo[n] = make_float2(fdh2e, (float)cc);
    }
    __syncthreads();

    const float wcolf = (float)tid;
    const int* base = targets + (size_t)b * NCH * HWSZ + hrow * WW + tid;

    int   tsum = 0;
    float imp  = 0.f;

    #pragma unroll 16
    for (int n = 0; n < NCH; ++n) {
        const int    v = base[(size_t)n * HWSZ];    // coalesced 256 B/wave
        const float2 c = cinfo[n];                  // LDS broadcast
        const float fdw = wcolf - c.y;
        const float f   = __builtin_fmaf(fdw, fdw, c.x);
        imp = __builtin_fmaf((float)v, __builtin_amdgcn_rcpf(f), imp);
        tsum += v;
    }

    // --- epilogue: importance coeff (~tsum bitwise-NOT semantics) + BCE
    const float it = __builtin_fmaf((float)(~tsum), 0.5f, imp);

    const float x   = pred[b * HWSZ + hrow * WW + tid];
    const float bce = fmaxf(x, 0.f) - x * (float)tsum + log1pf(expf(-fabsf(x)));

    float contrib = bce * it;

    // --- block reduction: wave64 shuffle, then 4-wave LDS combine
    #pragma unroll
    for (int o = 32; o > 0; o >>= 1) contrib += __shfl_down(contrib, o, 64);
    const int wave = tid >> 6;
    if ((tid & 63) == 0) wsum[wave] = contrib;
    __syncthreads();
    if (tid == 0) {
        const float s = wsum[0] + wsum[1] + wsum[2] + wsum[3];
        atomicAdd(out, s * (1.0f / (float)NPIX));
    }
}

extern "C" void kernel_launch(void* const* d_in, const int* in_sizes, int n_in,
                              void* d_out, int out_size, void* d_ws, size_t ws_size,
                              hipStream_t stream)
{
    const float* pred = (const float*)d_in[0];               // [B,H,W] f32
    const int*   tc   = (const int*)d_in[1];                 // [B,N,H,W] i32
    const int*   tg   = (const int*)d_in[2];                 // [B,N,H,W] i32
    const unsigned char* pm = (const unsigned char*)d_in[3]; // [B,N] bool
    float* out   = (float*)d_out;
    int* centers = (int*)d_ws;                               // 1024 ints

    find_centers<<<BATCH * NCH, 256, 0, stream>>>(tc, centers, out);
    loss_kernel<<<BATCH * HH, 256, 0, stream>>>(pred, tg, pm, centers, out);
}